// Round 1
// baseline (6958.067 us; speedup 1.0000x reference)
//
#include <hip/hip_runtime.h>
#include <hip/hip_bf16.h>
#include <math.h>

#define Bq   8
#define Nq   4096
#define DIMq 1024
#define CDq  512
#define Kq   8192
#define Mq   32768   // B*N

#define TAU      1.0e-2f
#define FLAGCAP  4096

// ---------------- seminorm: sem[k] = 0.5*||embed[k]||^2 (f64 accum) ----------------
__global__ __launch_bounds__(256) void seminorm_kernel(const float* __restrict__ embed,
                                                       float* __restrict__ sem) {
  int wid  = blockIdx.x * 4 + (threadIdx.x >> 6);
  int lane = threadIdx.x & 63;
  const float* e = embed + (size_t)wid * CDq;
  double s = 0.0;
#pragma unroll
  for (int j = 0; j < 2; ++j) {
    float4 v = *(const float4*)(e + j * 256 + lane * 4);
    s += (double)v.x * v.x + (double)v.y * v.y + (double)v.z * v.z + (double)v.w * v.w;
  }
#pragma unroll
  for (int off = 32; off; off >>= 1) s += __shfl_down(s, off, 64);
  if (lane == 0) sem[wid] = (float)(0.5 * s);
}

// ---------------- generic f32 GEMM + bias: C[M][N] = A[M][Kd] @ Bw[Kd][N] + bias ---
// BM=64, BN=128, BK=16, 256 threads, 4x8 micro-tile. GATHER: A-row = A[gidx[row]].
template <bool GATHER>
__global__ __launch_bounds__(256) void gemm_bias_kernel(
    const float* __restrict__ A, const float* __restrict__ Bw,
    const float* __restrict__ bias, float* __restrict__ C,
    const int* __restrict__ gidx, int N, int Kd) {
  __shared__ float As[16][68];
  __shared__ float Bs[16][132];
  const int t = threadIdx.x, tx = t & 15, ty = t >> 4;
  const int rowBase = blockIdx.y * 64;
  const int colBase = blockIdx.x * 128;
  const int rA = t >> 2, kqA = (t & 3) * 4;   // A staging: 1 float4/thread
  const int kB = t >> 4, cB = (t & 15) * 8;   // B staging: 2 float4/thread
  const float* Arow;
  if (GATHER) Arow = A + (size_t)gidx[rowBase + rA] * Kd;
  else        Arow = A + (size_t)(rowBase + rA) * Kd;
  const float* Bp = Bw + (size_t)kB * N + colBase + cB;
  float acc[4][8] = {};
  for (int kt = 0; kt < Kd; kt += 16) {
    float4 av = *(const float4*)(Arow + kt + kqA);
    float4 b0 = *(const float4*)(Bp + (size_t)kt * N);
    float4 b1 = *(const float4*)(Bp + (size_t)kt * N + 4);
    __syncthreads();
    As[kqA + 0][rA] = av.x; As[kqA + 1][rA] = av.y;
    As[kqA + 2][rA] = av.z; As[kqA + 3][rA] = av.w;
    *(float4*)&Bs[kB][cB]     = b0;
    *(float4*)&Bs[kB][cB + 4] = b1;
    __syncthreads();
#pragma unroll
    for (int kk = 0; kk < 16; ++kk) {
      float4 a  = *(const float4*)&As[kk][ty * 4];
      float4 p0 = *(const float4*)&Bs[kk][tx * 4];
      float4 p1 = *(const float4*)&Bs[kk][64 + tx * 4];
      float ar[4] = {a.x, a.y, a.z, a.w};
      float br[8] = {p0.x, p0.y, p0.z, p0.w, p1.x, p1.y, p1.z, p1.w};
#pragma unroll
      for (int i = 0; i < 4; ++i)
#pragma unroll
        for (int j = 0; j < 8; ++j) acc[i][j] = fmaf(ar[i], br[j], acc[i][j]);
    }
  }
  float4 bi0 = *(const float4*)(bias + colBase + tx * 4);
  float4 bi1 = *(const float4*)(bias + colBase + 64 + tx * 4);
#pragma unroll
  for (int i = 0; i < 4; ++i) {
    int row = rowBase + ty * 4 + i;
    float4 o0 = {acc[i][0] + bi0.x, acc[i][1] + bi0.y, acc[i][2] + bi0.z, acc[i][3] + bi0.w};
    float4 o1 = {acc[i][4] + bi1.x, acc[i][5] + bi1.y, acc[i][6] + bi1.z, acc[i][7] + bi1.w};
    *(float4*)(C + (size_t)row * N + colBase + tx * 4)      = o0;
    *(float4*)(C + (size_t)row * N + colBase + 64 + tx * 4) = o1;
  }
}

// ---------------- dist + argmax: score = xp.e - 0.5||e||^2, running top-2/row ------
__global__ __launch_bounds__(256) void dist_argmax_kernel(
    const float* __restrict__ xp, const float* __restrict__ embed,
    const float* __restrict__ sem, int* __restrict__ ind,
    int* __restrict__ flag_list, int* __restrict__ flag_cnt) {
  __shared__ union UU {
    struct { float As[16][68]; float Bs[16][132]; } s;            // 12800 B
    struct { float b1[64][16]; float b2[64][16]; int ix[64][16]; } r;  // 12288 B
  } u;
  const int t = threadIdx.x, tx = t & 15, ty = t >> 4;
  const int rowBase = blockIdx.x * 64;
  const int rA = t >> 2, kqA = (t & 3) * 4;   // A staging
  const int cb = t >> 1, kqB = (t & 1) * 8;   // B staging (transpose)
  const float* Arow = xp + (size_t)(rowBase + rA) * CDq;
  float best1[4], best2[4]; int bidx[4];
#pragma unroll
  for (int i = 0; i < 4; ++i) { best1[i] = -INFINITY; best2[i] = -INFINITY; bidx[i] = 0; }

  for (int nc = 0; nc < Kq; nc += 128) {
    float acc[4][8] = {};
    const float* Brow = embed + (size_t)(nc + cb) * CDq + kqB;
    for (int kt = 0; kt < CDq; kt += 16) {
      float4 av  = *(const float4*)(Arow + kt + kqA);
      float4 bv0 = *(const float4*)(Brow + kt);
      float4 bv1 = *(const float4*)(Brow + kt + 4);
      __syncthreads();
      u.s.As[kqA + 0][rA] = av.x; u.s.As[kqA + 1][rA] = av.y;
      u.s.As[kqA + 2][rA] = av.z; u.s.As[kqA + 3][rA] = av.w;
      u.s.Bs[kqB + 0][cb] = bv0.x; u.s.Bs[kqB + 1][cb] = bv0.y;
      u.s.Bs[kqB + 2][cb] = bv0.z; u.s.Bs[kqB + 3][cb] = bv0.w;
      u.s.Bs[kqB + 4][cb] = bv1.x; u.s.Bs[kqB + 5][cb] = bv1.y;
      u.s.Bs[kqB + 6][cb] = bv1.z; u.s.Bs[kqB + 7][cb] = bv1.w;
      __syncthreads();
#pragma unroll
      for (int kk = 0; kk < 16; ++kk) {
        float4 a  = *(const float4*)&u.s.As[kk][ty * 4];
        float4 p0 = *(const float4*)&u.s.Bs[kk][tx * 4];
        float4 p1 = *(const float4*)&u.s.Bs[kk][64 + tx * 4];
        float ar[4] = {a.x, a.y, a.z, a.w};
        float br[8] = {p0.x, p0.y, p0.z, p0.w, p1.x, p1.y, p1.z, p1.w};
#pragma unroll
        for (int i = 0; i < 4; ++i)
#pragma unroll
          for (int j = 0; j < 8; ++j) acc[i][j] = fmaf(ar[i], br[j], acc[i][j]);
      }
    }
    float4 s0 = *(const float4*)(sem + nc + tx * 4);
    float4 s1 = *(const float4*)(sem + nc + 64 + tx * 4);
    float sv[8] = {s0.x, s0.y, s0.z, s0.w, s1.x, s1.y, s1.z, s1.w};
#pragma unroll
    for (int i = 0; i < 4; ++i) {
#pragma unroll
      for (int j = 0; j < 8; ++j) {   // ascending column order -> first-max kept
        float sc = acc[i][j] - sv[j];
        int c = nc + (j < 4 ? tx * 4 + j : 64 + tx * 4 + (j - 4));
        if (sc > best1[i]) { best2[i] = best1[i]; best1[i] = sc; bidx[i] = c; }
        else if (sc > best2[i]) best2[i] = sc;
      }
    }
  }
  __syncthreads();
#pragma unroll
  for (int i = 0; i < 4; ++i) {
    u.r.b1[ty * 4 + i][tx] = best1[i];
    u.r.b2[ty * 4 + i][tx] = best2[i];
    u.r.ix[ty * 4 + i][tx] = bidx[i];
  }
  __syncthreads();
  if (t < 64) {
    float g1 = -INFINITY, g2 = -INFINITY; int gi = 0;
#pragma unroll
    for (int q = 0; q < 16; ++q) {
      float b = u.r.b1[t][q]; float s2 = u.r.b2[t][q]; int ix = u.r.ix[t][q];
      if (b > g1)      { g2 = fmaxf(g1, s2); g1 = b; gi = ix; }
      else if (b == g1){ if (ix < gi) gi = ix; g2 = fmaxf(g2, fmaxf(b, s2)); }
      else             { g2 = fmaxf(g2, b); }
    }
    int row = rowBase + t;
    ind[row] = gi;
    if (g1 - g2 < TAU) {
      int pos = atomicAdd(flag_cnt, 1);
      if (pos < FLAGCAP) flag_list[pos] = row;
    }
  }
}

// ---------------- fp64 rescue of near-tie rows ----------------
__global__ __launch_bounds__(256) void rescue_kernel(
    const float* __restrict__ x, const float* __restrict__ W_in,
    const float* __restrict__ b_in, const float* __restrict__ embed,
    int* __restrict__ ind, const int* __restrict__ flag_list,
    const int* __restrict__ flag_cnt) {
  __shared__ double xps[CDq];
  __shared__ double rb[256];
  __shared__ int ri[256];
  int cnt = *flag_cnt; if (cnt > FLAGCAP) cnt = FLAGCAP;
  for (int f = blockIdx.x; f < cnt; f += gridDim.x) {
    int row = flag_list[f];
    const float* xr = x + (size_t)row * DIMq;
    for (int c = threadIdx.x; c < CDq; c += 256) {
      double s0 = 0, s1 = 0;
      const float* wc = W_in + c;
      for (int d = 0; d < DIMq; d += 2) {
        s0 += (double)xr[d]     * (double)wc[(size_t)d * CDq];
        s1 += (double)xr[d + 1] * (double)wc[(size_t)(d + 1) * CDq];
      }
      xps[c] = s0 + s1 + (double)b_in[c];
    }
    __syncthreads();
    double best = -1e300; int bi = 0;
    for (int c0 = threadIdx.x; c0 < Kq; c0 += 256) {
      const float* e = embed + (size_t)c0 * CDq;
      double s0 = 0, s1 = 0, s2 = 0, s3 = 0;
      for (int d = 0; d < CDq; d += 4) {
        double e0 = e[d], e1 = e[d + 1], e2 = e[d + 2], e3 = e[d + 3];
        s0 += e0 * (xps[d]     - 0.5 * e0);
        s1 += e1 * (xps[d + 1] - 0.5 * e1);
        s2 += e2 * (xps[d + 2] - 0.5 * e2);
        s3 += e3 * (xps[d + 3] - 0.5 * e3);
      }
      double s = (s0 + s1) + (s2 + s3);
      if (s > best) { best = s; bi = c0; }
    }
    rb[threadIdx.x] = best; ri[threadIdx.x] = bi;
    __syncthreads();
    if (threadIdx.x == 0) {
      double g = -1e300; int gi = 0;
      for (int q = 0; q < 256; ++q)
        if (rb[q] > g || (rb[q] == g && ri[q] < gi)) { g = rb[q]; gi = ri[q]; }
      ind[row] = gi;
    }
    __syncthreads();
  }
}

// ---------------- ind(int) -> float output ----------------
__global__ __launch_bounds__(256) void ind_to_float_kernel(const int* __restrict__ ind,
                                                           float* __restrict__ dst) {
  int i = blockIdx.x * 256 + threadIdx.x;
  if (i < Mq) dst[i] = (float)ind[i];
}

// ---------------- commit loss: partial sums ----------------
__global__ __launch_bounds__(256) void loss_kernel(const float* __restrict__ xp,
                                                   const float* __restrict__ embed,
                                                   const int* __restrict__ ind,
                                                   float* __restrict__ partials) {
  int b = blockIdx.x;  // 1024 blocks, 32 rows each
  float s = 0.f;
  for (int r0 = 0; r0 < 32; ++r0) {
    int row = b * 32 + r0;
    const float* xr = xp + (size_t)row * CDq;
    const float* er = embed + (size_t)ind[row] * CDq;
    for (int c = threadIdx.x; c < CDq; c += 256) {
      float d = er[c] - xr[c];
      s = fmaf(d, d, s);
    }
  }
  __shared__ float red[256];
  red[threadIdx.x] = s; __syncthreads();
  for (int off = 128; off; off >>= 1) {
    if (threadIdx.x < off) red[threadIdx.x] += red[threadIdx.x + off];
    __syncthreads();
  }
  if (threadIdx.x == 0) partials[b] = red[0];
}

__global__ __launch_bounds__(256) void loss_final_kernel(const float* __restrict__ partials,
                                                         float* __restrict__ out_loss) {
  __shared__ double red[256];
  double s = 0;
  for (int i = threadIdx.x; i < 1024; i += 256) s += (double)partials[i];
  red[threadIdx.x] = s; __syncthreads();
  for (int off = 128; off; off >>= 1) {
    if (threadIdx.x < off) red[threadIdx.x] += red[threadIdx.x + off];
    __syncthreads();
  }
  if (threadIdx.x == 0) *out_loss = (float)(red[0] / 16777216.0);
}

extern "C" void kernel_launch(void* const* d_in, const int* in_sizes, int n_in,
                              void* d_out, int out_size, void* d_ws, size_t ws_size,
                              hipStream_t stream) {
  const float* x     = (const float*)d_in[0];
  const float* W_in  = (const float*)d_in[1];
  const float* b_in  = (const float*)d_in[2];
  const float* embed = (const float*)d_in[3];
  const float* W_out = (const float*)d_in[4];
  const float* b_out = (const float*)d_in[5];

  float* out      = (float*)d_out;
  float* xp       = (float*)d_out;                  // scratch overlay (dead before proj_out)
  float* ind_f    = out + (size_t)Mq * DIMq;        // 33554432
  float* loss_out = ind_f + Mq;                     // 33587200

  char* ws        = (char*)d_ws;
  int*   flag_cnt  = (int*)ws;
  int*   ind       = (int*)(ws + 64);
  int*   flag_list = (int*)(ws + 64 + (size_t)Mq * 4);
  float* sem       = (float*)(ws + 64 + (size_t)Mq * 4 + FLAGCAP * 4);
  float* partials  = (float*)(ws + 64 + (size_t)Mq * 4 + FLAGCAP * 4 + (size_t)Kq * 4);

  (void)hipMemsetAsync(flag_cnt, 0, 4, stream);
  seminorm_kernel<<<Kq / 4, 256, 0, stream>>>(embed, sem);
  gemm_bias_kernel<false><<<dim3(CDq / 128, Mq / 64), 256, 0, stream>>>(
      x, W_in, b_in, xp, nullptr, CDq, DIMq);
  dist_argmax_kernel<<<Mq / 64, 256, 0, stream>>>(xp, embed, sem, ind, flag_list, flag_cnt);
  rescue_kernel<<<256, 256, 0, stream>>>(x, W_in, b_in, embed, ind, flag_list, flag_cnt);
  ind_to_float_kernel<<<Mq / 256, 256, 0, stream>>>(ind, ind_f);
  loss_kernel<<<1024, 256, 0, stream>>>(xp, embed, ind, partials);
  loss_final_kernel<<<1, 256, 0, stream>>>(partials, loss_out);
  gemm_bias_kernel<true><<<dim3(DIMq / 128, Mq / 64), 256, 0, stream>>>(
      embed, W_out, b_out, out, ind, DIMq, CDq);
}

// Round 2
// 2952.088 us; speedup vs baseline: 2.3570x; 2.3570x over previous
//
#include <hip/hip_runtime.h>
#include <hip/hip_bf16.h>
#include <math.h>

#define DIMq 1024
#define CDq  512
#define Kq   8192
#define Mq   32768   // B*N

#define TAU      1.0e-2f
#define FLAGCAP  4096

typedef __attribute__((ext_vector_type(8))) short bf16x8;
typedef __attribute__((ext_vector_type(4))) float f32x4;
typedef __attribute__((ext_vector_type(4))) unsigned short u16x4;

__device__ __forceinline__ ushort bf16rne(float v) {
  unsigned u = __float_as_uint(v);
  return (ushort)((u + 0x7FFFu + ((u >> 16) & 1u)) >> 16);
}
__device__ __forceinline__ float bf16tof(ushort h) {
  return __uint_as_float(((unsigned)h) << 16);
}

// ---------------- embed f32 -> (eh, el) split bf16 ----------------
__global__ __launch_bounds__(256) void embed_conv_kernel(const float* __restrict__ e,
                                                         ushort* __restrict__ eh,
                                                         ushort* __restrict__ el) {
  size_t i = ((size_t)blockIdx.x * 256 + threadIdx.x) * 8;
  float4 v0 = *(const float4*)(e + i);
  float4 v1 = *(const float4*)(e + i + 4);
  float vv[8] = {v0.x, v0.y, v0.z, v0.w, v1.x, v1.y, v1.z, v1.w};
  u16x4 h0, h1, l0, l1;
#pragma unroll
  for (int j = 0; j < 4; ++j) {
    ushort hb = bf16rne(vv[j]);     h0[j] = hb; l0[j] = bf16rne(vv[j] - bf16tof(hb));
    ushort hc = bf16rne(vv[4 + j]); h1[j] = hc; l1[j] = bf16rne(vv[4 + j] - bf16tof(hc));
  }
  *(u16x4*)(eh + i) = h0; *(u16x4*)(eh + i + 4) = h1;
  *(u16x4*)(el + i) = l0; *(u16x4*)(el + i + 4) = l1;
}

// ---------------- seminorm: sem[k] = 0.5*||embed[k]||^2 (f64 accum) ----------------
__global__ __launch_bounds__(256) void seminorm_kernel(const float* __restrict__ embed,
                                                       float* __restrict__ sem) {
  int wid  = blockIdx.x * 4 + (threadIdx.x >> 6);
  int lane = threadIdx.x & 63;
  const float* e = embed + (size_t)wid * CDq;
  double s = 0.0;
#pragma unroll
  for (int j = 0; j < 2; ++j) {
    float4 v = *(const float4*)(e + j * 256 + lane * 4);
    s += (double)v.x * v.x + (double)v.y * v.y + (double)v.z * v.z + (double)v.w * v.w;
  }
#pragma unroll
  for (int off = 32; off; off >>= 1) s += __shfl_down(s, off, 64);
  if (lane == 0) sem[wid] = (float)(0.5 * s);
}

// ---------------- proj_in: xp = x@W_in + b_in, emitted as split bf16 (xph,xpl) -----
__global__ __launch_bounds__(256) void proj_in_kernel(
    const float* __restrict__ A, const float* __restrict__ Bw,
    const float* __restrict__ bias, ushort* __restrict__ xph, ushort* __restrict__ xpl) {
  __shared__ float As[16][68];
  __shared__ float Bs[16][132];
  const int t = threadIdx.x, tx = t & 15, ty = t >> 4;
  const int rowBase = blockIdx.y * 64;
  const int colBase = blockIdx.x * 128;
  const int rA = t >> 2, kqA = (t & 3) * 4;
  const int kB = t >> 4, cB = (t & 15) * 8;
  const float* Arow = A + (size_t)(rowBase + rA) * DIMq;
  const float* Bp = Bw + (size_t)kB * CDq + colBase + cB;
  float acc[4][8] = {};
  for (int kt = 0; kt < DIMq; kt += 16) {
    float4 av = *(const float4*)(Arow + kt + kqA);
    float4 b0 = *(const float4*)(Bp + (size_t)kt * CDq);
    float4 b1 = *(const float4*)(Bp + (size_t)kt * CDq + 4);
    __syncthreads();
    As[kqA + 0][rA] = av.x; As[kqA + 1][rA] = av.y;
    As[kqA + 2][rA] = av.z; As[kqA + 3][rA] = av.w;
    *(float4*)&Bs[kB][cB]     = b0;
    *(float4*)&Bs[kB][cB + 4] = b1;
    __syncthreads();
#pragma unroll
    for (int kk = 0; kk < 16; ++kk) {
      float4 a  = *(const float4*)&As[kk][ty * 4];
      float4 p0 = *(const float4*)&Bs[kk][tx * 4];
      float4 p1 = *(const float4*)&Bs[kk][64 + tx * 4];
      float ar[4] = {a.x, a.y, a.z, a.w};
      float br[8] = {p0.x, p0.y, p0.z, p0.w, p1.x, p1.y, p1.z, p1.w};
#pragma unroll
      for (int i = 0; i < 4; ++i)
#pragma unroll
        for (int j = 0; j < 8; ++j) acc[i][j] = fmaf(ar[i], br[j], acc[i][j]);
    }
  }
  float4 bi0 = *(const float4*)(bias + colBase + tx * 4);
  float4 bi1 = *(const float4*)(bias + colBase + 64 + tx * 4);
  float bb[8] = {bi0.x, bi0.y, bi0.z, bi0.w, bi1.x, bi1.y, bi1.z, bi1.w};
#pragma unroll
  for (int i = 0; i < 4; ++i) {
    size_t row = rowBase + ty * 4 + i;
    u16x4 h0, h1, l0, l1;
#pragma unroll
    for (int j = 0; j < 4; ++j) {
      float v0 = acc[i][j] + bb[j];
      float v1 = acc[i][4 + j] + bb[4 + j];
      ushort hb = bf16rne(v0); h0[j] = hb; l0[j] = bf16rne(v0 - bf16tof(hb));
      ushort hc = bf16rne(v1); h1[j] = hc; l1[j] = bf16rne(v1 - bf16tof(hc));
    }
    size_t o0 = row * CDq + colBase + tx * 4;
    *(u16x4*)(xph + o0) = h0; *(u16x4*)(xph + o0 + 64) = h1;
    *(u16x4*)(xpl + o0) = l0; *(u16x4*)(xpl + o0 + 64) = l1;
  }
}

// ---------------- generic f32 GEMM + bias (GATHER) for project_out -----------------
__global__ __launch_bounds__(256) void proj_out_kernel(
    const float* __restrict__ A, const float* __restrict__ Bw,
    const float* __restrict__ bias, float* __restrict__ C,
    const int* __restrict__ gidx) {
  __shared__ float As[16][68];
  __shared__ float Bs[16][132];
  const int t = threadIdx.x, tx = t & 15, ty = t >> 4;
  const int rowBase = blockIdx.y * 64;
  const int colBase = blockIdx.x * 128;
  const int rA = t >> 2, kqA = (t & 3) * 4;
  const int kB = t >> 4, cB = (t & 15) * 8;
  const float* Arow = A + (size_t)gidx[rowBase + rA] * CDq;
  const float* Bp = Bw + (size_t)kB * DIMq + colBase + cB;
  float acc[4][8] = {};
  for (int kt = 0; kt < CDq; kt += 16) {
    float4 av = *(const float4*)(Arow + kt + kqA);
    float4 b0 = *(const float4*)(Bp + (size_t)kt * DIMq);
    float4 b1 = *(const float4*)(Bp + (size_t)kt * DIMq + 4);
    __syncthreads();
    As[kqA + 0][rA] = av.x; As[kqA + 1][rA] = av.y;
    As[kqA + 2][rA] = av.z; As[kqA + 3][rA] = av.w;
    *(float4*)&Bs[kB][cB]     = b0;
    *(float4*)&Bs[kB][cB + 4] = b1;
    __syncthreads();
#pragma unroll
    for (int kk = 0; kk < 16; ++kk) {
      float4 a  = *(const float4*)&As[kk][ty * 4];
      float4 p0 = *(const float4*)&Bs[kk][tx * 4];
      float4 p1 = *(const float4*)&Bs[kk][64 + tx * 4];
      float ar[4] = {a.x, a.y, a.z, a.w};
      float br[8] = {p0.x, p0.y, p0.z, p0.w, p1.x, p1.y, p1.z, p1.w};
#pragma unroll
      for (int i = 0; i < 4; ++i)
#pragma unroll
        for (int j = 0; j < 8; ++j) acc[i][j] = fmaf(ar[i], br[j], acc[i][j]);
    }
  }
  float4 bi0 = *(const float4*)(bias + colBase + tx * 4);
  float4 bi1 = *(const float4*)(bias + colBase + 64 + tx * 4);
#pragma unroll
  for (int i = 0; i < 4; ++i) {
    int row = rowBase + ty * 4 + i;
    float4 o0 = {acc[i][0] + bi0.x, acc[i][1] + bi0.y, acc[i][2] + bi0.z, acc[i][3] + bi0.w};
    float4 o1 = {acc[i][4] + bi1.x, acc[i][5] + bi1.y, acc[i][6] + bi1.z, acc[i][7] + bi1.w};
    *(float4*)(C + (size_t)row * DIMq + colBase + tx * 4)      = o0;
    *(float4*)(C + (size_t)row * DIMq + colBase + 64 + tx * 4) = o1;
  }
}

// ---------------- dist via split-bf16 MFMA + running top-2 ----------------
// grid 512 = 256 row-blocks x 2 codebook halves. block = 256 thr (4 waves 2x2),
// tile 128 rows x 128 codes, BK=32. score = xp.e - 0.5||e||^2 with
// xp.e ~= xh.eh + xh.el + xl.eh (f32 accum). LDS 64KB: 2 x (Ah|Al|Bh|Bl)[128][32]bf16.
__global__ __launch_bounds__(256) void dist_mfma_kernel(
    const ushort* __restrict__ xph, const ushort* __restrict__ xpl,
    const ushort* __restrict__ eh,  const ushort* __restrict__ el,
    const float* __restrict__ sem,
    float* __restrict__ pb1, float* __restrict__ pb2, int* __restrict__ pidx) {
  __shared__ __align__(16) char smem[65536];
  const int t = threadIdx.x;
  const int wave = t >> 6, lane = t & 63;
  const int wm = wave >> 1, wn = wave & 1;
  const int lx = lane & 15, lg = lane >> 4;
  const int rb = (int)blockIdx.x >> 1, hpart = (int)blockIdx.x & 1;
  const size_t arow0 = (size_t)rb * 128;
  const int code0 = hpart * 4096;

  // staging constants: slot p -> row r=p>>2, swizzled chunk c=(p&3)^((r>>1)&3)
  size_t aoff[2], boff[2];
#pragma unroll
  for (int s = 0; s < 2; ++s) {
    int p = t + s * 256;
    int r = p >> 2;
    int c = (p & 3) ^ ((r >> 1) & 3);
    aoff[s] = (arow0 + r) * CDq + c * 8;
    boff[s] = ((size_t)code0 + r) * CDq + c * 8;
  }
  // fragment read byte-offsets (within an 8KB tile)
  int offm[4], offn[4];
#pragma unroll
  for (int f = 0; f < 4; ++f) {
    int rm = wm * 64 + f * 16 + lx;
    offm[f] = rm * 64 + ((lg ^ ((rm >> 1) & 3)) * 16);
    int rn = wn * 64 + f * 16 + lx;
    offn[f] = rn * 64 + ((lg ^ ((rn >> 1) & 3)) * 16);
  }

  float b1[16], b2[16]; int ic[16];
#pragma unroll
  for (int s = 0; s < 16; ++s) { b1[s] = -INFINITY; b2[s] = -INFINITY; ic[s] = 0; }

#define STAGE(BUFB, TL, K0)                                                              \
  {                                                                                      \
    char* _bs = smem + (BUFB);                                                           \
    size_t _tb = (size_t)(TL) * 65536 + (K0);                                            \
    _Pragma("unroll")                                                                    \
    for (int s = 0; s < 2; ++s) {                                                        \
      int _p16 = (t + s * 256) * 16;                                                     \
      __builtin_amdgcn_global_load_lds(                                                  \
        (const __attribute__((address_space(1))) unsigned int*)(xph + aoff[s] + (K0)),   \
        (__attribute__((address_space(3))) unsigned int*)(_bs + _p16), 16, 0, 0);        \
      __builtin_amdgcn_global_load_lds(                                                  \
        (const __attribute__((address_space(1))) unsigned int*)(xpl + aoff[s] + (K0)),   \
        (__attribute__((address_space(3))) unsigned int*)(_bs + 8192 + _p16), 16, 0, 0); \
      __builtin_amdgcn_global_load_lds(                                                  \
        (const __attribute__((address_space(1))) unsigned int*)(eh + boff[s] + _tb),     \
        (__attribute__((address_space(3))) unsigned int*)(_bs + 16384 + _p16), 16, 0, 0);\
      __builtin_amdgcn_global_load_lds(                                                  \
        (const __attribute__((address_space(1))) unsigned int*)(el + boff[s] + _tb),     \
        (__attribute__((address_space(3))) unsigned int*)(_bs + 24576 + _p16), 16, 0, 0);\
    }                                                                                    \
  }

  int buf = 0;
  STAGE(0, 0, 0)
#pragma unroll 1
  for (int tile = 0; tile < 32; ++tile) {
    f32x4 acc[4][4];
#pragma unroll
    for (int i = 0; i < 4; ++i)
#pragma unroll
      for (int j = 0; j < 4; ++j) acc[i][j] = (f32x4){0.f, 0.f, 0.f, 0.f};
#pragma unroll 1
    for (int kt = 0; kt < 16; ++kt) {
      __syncthreads();
      int nt = tile, nk = kt + 1;
      if (nk == 16) { nt = tile + 1; nk = 0; }
      if (nt < 32) STAGE((buf ^ 1) * 32768, nt, nk * 32)
      const char* bs = smem + buf * 32768;
      bf16x8 ah[4], al_[4], bh[4], bl_[4];
#pragma unroll
      for (int f = 0; f < 4; ++f) {
        ah[f]  = *(const bf16x8*)(bs + offm[f]);
        al_[f] = *(const bf16x8*)(bs + 8192 + offm[f]);
        bh[f]  = *(const bf16x8*)(bs + 16384 + offn[f]);
        bl_[f] = *(const bf16x8*)(bs + 24576 + offn[f]);
      }
#pragma unroll
      for (int i = 0; i < 4; ++i)
#pragma unroll
        for (int j = 0; j < 4; ++j) {
          acc[i][j] = __builtin_amdgcn_mfma_f32_16x16x32_bf16(ah[i],  bh[j],  acc[i][j], 0, 0, 0);
          acc[i][j] = __builtin_amdgcn_mfma_f32_16x16x32_bf16(ah[i],  bl_[j], acc[i][j], 0, 0, 0);
          acc[i][j] = __builtin_amdgcn_mfma_f32_16x16x32_bf16(al_[i], bh[j],  acc[i][j], 0, 0, 0);
        }
      buf ^= 1;
    }
    // epilogue: subtract seminorm, update running top-2 (codes ascending in nf)
#pragma unroll
    for (int nf = 0; nf < 4; ++nf) {
      int code = code0 + tile * 128 + wn * 64 + nf * 16 + lx;
      float sv = sem[code];
#pragma unroll
      for (int mf = 0; mf < 4; ++mf)
#pragma unroll
        for (int q = 0; q < 4; ++q) {
          float s = acc[mf][nf][q] - sv;
          int sl = mf * 4 + q;
          if (s > b1[sl]) { b2[sl] = b1[sl]; b1[sl] = s; ic[sl] = code; }
          else if (s > b2[sl]) b2[sl] = s;
        }
    }
  }
#undef STAGE

  // cross-lane (lx) top-2 reduce per slot via shuffles within 16-lane groups
#pragma unroll
  for (int s = 0; s < 16; ++s) {
#pragma unroll
    for (int m = 1; m < 16; m <<= 1) {
      float o1 = __shfl_xor(b1[s], m, 16);
      float o2 = __shfl_xor(b2[s], m, 16);
      int   oi = __shfl_xor(ic[s], m, 16);
      bool ow = (o1 > b1[s]) || (o1 == b1[s] && oi < ic[s]);
      float l1 = ow ? b1[s] : o1;
      float w2 = ow ? o2 : b2[s];
      if (ow) { b1[s] = o1; ic[s] = oi; }
      b2[s] = fmaxf(w2, l1);
    }
  }
  __syncthreads();
  float* rb1 = (float*)smem;            // [2 wm][64 r][2 wn]
  float* rb2 = (float*)(smem + 1024);
  int*   ric = (int*)(smem + 2048);
  if (lx == 0) {
#pragma unroll
    for (int mf = 0; mf < 4; ++mf)
#pragma unroll
      for (int q = 0; q < 4; ++q) {
        int r64 = mf * 16 + lg * 4 + q;
        int o = wm * 128 + r64 * 2 + wn;
        int sl = mf * 4 + q;
        rb1[o] = b1[sl]; rb2[o] = b2[sl]; ric[o] = ic[sl];
      }
  }
  __syncthreads();
  if (t < 128) {
    int o0 = t * 2;
    float a1 = rb1[o0], a2 = rb2[o0]; int ai = ric[o0];
    float c1 = rb1[o0 + 1], c2 = rb2[o0 + 1]; int ci = ric[o0 + 1];
    float g1, g2; int gi;
    if (c1 > a1 || (c1 == a1 && ci < ai)) { g1 = c1; gi = ci; g2 = fmaxf(c2, a1); }
    else                                   { g1 = a1; gi = ai; g2 = fmaxf(a2, c1); }
    size_t o = (size_t)hpart * Mq + rb * 128 + t;
    pb1[o] = g1; pb2[o] = g2; pidx[o] = gi;
  }
}

// ---------------- merge codebook halves -> ind, ind_f, near-tie flags ----------------
__global__ __launch_bounds__(256) void merge_final_kernel(
    const float* __restrict__ pb1, const float* __restrict__ pb2, const int* __restrict__ pidx,
    int* __restrict__ ind, float* __restrict__ ind_f,
    int* __restrict__ flag_list, int* __restrict__ flag_cnt) {
  int row = blockIdx.x * 256 + threadIdx.x;
  if (row >= Mq) return;
  float a1 = pb1[row], a2 = pb2[row]; int ai = pidx[row];
  float c1 = pb1[Mq + row], c2 = pb2[Mq + row]; int ci = pidx[Mq + row];
  float g1, g2; int gi;
  if (c1 > a1 || (c1 == a1 && ci < ai)) { g1 = c1; gi = ci; g2 = fmaxf(c2, a1); }
  else                                   { g1 = a1; gi = ai; g2 = fmaxf(a2, c1); }
  ind[row] = gi;
  ind_f[row] = (float)gi;
  if (g1 - g2 < TAU) {
    int pos = atomicAdd(flag_cnt, 1);
    if (pos < FLAGCAP) flag_list[pos] = row;
  }
}

// ---------------- fp64 rescue of near-tie rows ----------------
__global__ __launch_bounds__(256) void rescue_kernel(
    const float* __restrict__ x, const float* __restrict__ W_in,
    const float* __restrict__ b_in, const float* __restrict__ embed,
    int* __restrict__ ind, float* __restrict__ ind_f,
    const int* __restrict__ flag_list, const int* __restrict__ flag_cnt) {
  __shared__ double xps[CDq];
  __shared__ double rb[256];
  __shared__ int ri[256];
  int cnt = *flag_cnt; if (cnt > FLAGCAP) cnt = FLAGCAP;
  for (int f = blockIdx.x; f < cnt; f += gridDim.x) {
    int row = flag_list[f];
    const float* xr = x + (size_t)row * DIMq;
    for (int c = threadIdx.x; c < CDq; c += 256) {
      double s0 = 0, s1 = 0;
      const float* wc = W_in + c;
      for (int d = 0; d < DIMq; d += 2) {
        s0 += (double)xr[d]     * (double)wc[(size_t)d * CDq];
        s1 += (double)xr[d + 1] * (double)wc[(size_t)(d + 1) * CDq];
      }
      xps[c] = s0 + s1 + (double)b_in[c];
    }
    __syncthreads();
    double best = -1e300; int bi = 0;
    for (int c0 = threadIdx.x; c0 < Kq; c0 += 256) {
      const float* e = embed + (size_t)c0 * CDq;
      double s0 = 0, s1 = 0, s2 = 0, s3 = 0;
      for (int d = 0; d < CDq; d += 4) {
        double e0 = e[d], e1 = e[d + 1], e2 = e[d + 2], e3 = e[d + 3];
        s0 += e0 * (xps[d]     - 0.5 * e0);
        s1 += e1 * (xps[d + 1] - 0.5 * e1);
        s2 += e2 * (xps[d + 2] - 0.5 * e2);
        s3 += e3 * (xps[d + 3] - 0.5 * e3);
      }
      double s = (s0 + s1) + (s2 + s3);
      if (s > best) { best = s; bi = c0; }
    }
    rb[threadIdx.x] = best; ri[threadIdx.x] = bi;
    __syncthreads();
    if (threadIdx.x == 0) {
      double g = -1e300; int gi = 0;
      for (int q = 0; q < 256; ++q)
        if (rb[q] > g || (rb[q] == g && ri[q] < gi)) { g = rb[q]; gi = ri[q]; }
      ind[row] = gi;
      ind_f[row] = (float)gi;
    }
    __syncthreads();
  }
}

// ---------------- commit loss (xp reconstructed from split bf16) ----------------
__global__ __launch_bounds__(256) void loss_kernel(const ushort* __restrict__ xph,
                                                   const ushort* __restrict__ xpl,
                                                   const float* __restrict__ embed,
                                                   const int* __restrict__ ind,
                                                   float* __restrict__ partials) {
  int b = blockIdx.x;  // 1024 blocks, 32 rows each
  float s = 0.f;
  for (int r0 = 0; r0 < 32; ++r0) {
    int row = b * 32 + r0;
    const ushort* xh = xph + (size_t)row * CDq;
    const ushort* xl = xpl + (size_t)row * CDq;
    const float* er = embed + (size_t)ind[row] * CDq;
    for (int c = threadIdx.x; c < CDq; c += 256) {
      float d = er[c] - (bf16tof(xh[c]) + bf16tof(xl[c]));
      s = fmaf(d, d, s);
    }
  }
  __shared__ float red[256];
  red[threadIdx.x] = s; __syncthreads();
  for (int off = 128; off; off >>= 1) {
    if (threadIdx.x < off) red[threadIdx.x] += red[threadIdx.x + off];
    __syncthreads();
  }
  if (threadIdx.x == 0) partials[b] = red[0];
}

__global__ __launch_bounds__(256) void loss_final_kernel(const float* __restrict__ partials,
                                                         float* __restrict__ out_loss) {
  __shared__ double red[256];
  double s = 0;
  for (int i = threadIdx.x; i < 1024; i += 256) s += (double)partials[i];
  red[threadIdx.x] = s; __syncthreads();
  for (int off = 128; off; off >>= 1) {
    if (threadIdx.x < off) red[threadIdx.x] += red[threadIdx.x + off];
    __syncthreads();
  }
  if (threadIdx.x == 0) *out_loss = (float)(red[0] / 16777216.0);
}

extern "C" void kernel_launch(void* const* d_in, const int* in_sizes, int n_in,
                              void* d_out, int out_size, void* d_ws, size_t ws_size,
                              hipStream_t stream) {
  const float* x     = (const float*)d_in[0];
  const float* W_in  = (const float*)d_in[1];
  const float* b_in  = (const float*)d_in[2];
  const float* embed = (const float*)d_in[3];
  const float* W_out = (const float*)d_in[4];
  const float* b_out = (const float*)d_in[5];

  char* ob = (char*)d_out;
  float*  out      = (float*)d_out;
  ushort* xph      = (ushort*)ob;                       // [Mq][CDq] 32MB (dead before proj_out)
  ushort* xpl      = (ushort*)(ob + (size_t)(32u << 20));
  ushort* eh       = (ushort*)(ob + (size_t)(64u << 20)); // 8MB
  ushort* el       = (ushort*)(ob + (size_t)(72u << 20));
  float*  pb1      = (float*)(ob + (size_t)(80u << 20));  // [2][Mq]
  float*  pb2      = (float*)(ob + (size_t)(81u << 20));
  int*    pidx     = (int*)  (ob + (size_t)(82u << 20));
  float*  ind_f    = out + (size_t)Mq * DIMq;
  float*  loss_out = ind_f + Mq;

  char* ws = (char*)d_ws;
  int*   flag_cnt  = (int*)ws;
  int*   ind       = (int*)(ws + 64);
  int*   flag_list = (int*)(ws + 64 + (size_t)Mq * 4);
  float* sem       = (float*)(ws + 64 + (size_t)Mq * 4 + FLAGCAP * 4);
  float* partials  = sem + Kq;

  (void)hipMemsetAsync(flag_cnt, 0, 4, stream);
  embed_conv_kernel<<<(Kq * CDq) / (256 * 8), 256, 0, stream>>>(embed, eh, el);
  seminorm_kernel<<<Kq / 4, 256, 0, stream>>>(embed, sem);
  proj_in_kernel<<<dim3(CDq / 128, Mq / 64), 256, 0, stream>>>(x, W_in, b_in, xph, xpl);
  dist_mfma_kernel<<<512, 256, 0, stream>>>(xph, xpl, eh, el, sem, pb1, pb2, pidx);
  merge_final_kernel<<<Mq / 256, 256, 0, stream>>>(pb1, pb2, pidx, ind, ind_f, flag_list, flag_cnt);
  rescue_kernel<<<256, 256, 0, stream>>>(x, W_in, b_in, embed, ind, ind_f, flag_list, flag_cnt);
  loss_kernel<<<1024, 256, 0, stream>>>(xph, xpl, embed, ind, partials);
  loss_final_kernel<<<1, 256, 0, stream>>>(partials, loss_out);
  proj_out_kernel<<<dim3(DIMq / 128, Mq / 64), 256, 0, stream>>>(embed, W_out, b_out, out, ind);
}

// Round 5
// 2712.641 us; speedup vs baseline: 2.5651x; 1.0883x over previous
//
#include <hip/hip_runtime.h>
#include <hip/hip_bf16.h>
#include <math.h>

#define DIMq 1024
#define CDq  512
#define Kq   8192
#define Mq   32768   // B*N

#define TAU      1.0e-2f
#define FLAGCAP  4096
#define MiB      (1u << 20)

typedef __attribute__((ext_vector_type(8))) short bf16x8;
typedef __attribute__((ext_vector_type(4))) float f32x4;
typedef __attribute__((ext_vector_type(4))) unsigned short u16x4;

__device__ __forceinline__ ushort bf16rne(float v) {
  unsigned u = __float_as_uint(v);
  return (ushort)((u + 0x7FFFu + ((u >> 16) & 1u)) >> 16);
}
__device__ __forceinline__ float bf16tof(ushort h) {
  return __uint_as_float(((unsigned)h) << 16);
}

#define GL16(gp, lp)                                                       \
  __builtin_amdgcn_global_load_lds(                                        \
      (const __attribute__((address_space(1))) unsigned int*)(gp),         \
      (__attribute__((address_space(3))) unsigned int*)(lp), 16, 0, 0)

// ---------------- embed f32 -> (eh, el) split bf16 ----------------
__global__ __launch_bounds__(256) void embed_conv_kernel(const float* __restrict__ e,
                                                         ushort* __restrict__ eh,
                                                         ushort* __restrict__ el) {
  size_t i = ((size_t)blockIdx.x * 256 + threadIdx.x) * 8;
  float4 v0 = *(const float4*)(e + i);
  float4 v1 = *(const float4*)(e + i + 4);
  float vv[8] = {v0.x, v0.y, v0.z, v0.w, v1.x, v1.y, v1.z, v1.w};
  u16x4 h0, h1, l0, l1;
#pragma unroll
  for (int j = 0; j < 4; ++j) {
    ushort hb = bf16rne(vv[j]);     h0[j] = hb; l0[j] = bf16rne(vv[j] - bf16tof(hb));
    ushort hc = bf16rne(vv[4 + j]); h1[j] = hc; l1[j] = bf16rne(vv[4 + j] - bf16tof(hc));
  }
  *(u16x4*)(eh + i) = h0; *(u16x4*)(eh + i + 4) = h1;
  *(u16x4*)(el + i) = l0; *(u16x4*)(el + i + 4) = l1;
}

// ---------------- seminorm: sem[k] = 0.5*||embed[k]||^2 (f64 accum) ----------------
__global__ __launch_bounds__(256) void seminorm_kernel(const float* __restrict__ embed,
                                                       float* __restrict__ sem) {
  int wid  = blockIdx.x * 4 + (threadIdx.x >> 6);
  int lane = threadIdx.x & 63;
  const float* e = embed + (size_t)wid * CDq;
  double s = 0.0;
#pragma unroll
  for (int j = 0; j < 2; ++j) {
    float4 v = *(const float4*)(e + j * 256 + lane * 4);
    s += (double)v.x * v.x + (double)v.y * v.y + (double)v.z * v.z + (double)v.w * v.w;
  }
#pragma unroll
  for (int off = 32; off; off >>= 1) s += __shfl_down(s, off, 64);
  if (lane == 0) sem[wid] = (float)(0.5 * s);
}

// ---------------- transpose + split: dst[C][R] (bf16 hi/lo) = src[R][C] f32 --------
__global__ __launch_bounds__(256) void transpose_split_kernel(
    const float* __restrict__ src, ushort* __restrict__ dh, ushort* __restrict__ dl,
    int R, int C) {
  __shared__ float ts[64][65];
  int c0 = blockIdx.x * 64, r0 = blockIdx.y * 64;
#pragma unroll
  for (int i = 0; i < 16; ++i) {
    int idx = threadIdx.x + i * 256; int r = idx >> 6, c = idx & 63;
    ts[r][c] = src[(size_t)(r0 + r) * C + c0 + c];
  }
  __syncthreads();
#pragma unroll
  for (int i = 0; i < 16; ++i) {
    int idx = threadIdx.x + i * 256; int a = idx >> 6, b = idx & 63;
    float v = ts[b][a];
    ushort h = bf16rne(v);
    size_t o = (size_t)(c0 + a) * R + r0 + b;
    dh[o] = h; dl[o] = bf16rne(v - bf16tof(h));
  }
}

// ======== shared MFMA-GEMM geometry: 128x128 tile, BK=32, 4 waves, 3-term split ====
// LDS 32KB single buffer: Ah@0 Al@8K Bh@16K Bl@24K, each [128 rows][32 k] bf16,
// chunk-XOR swizzled: LDS slot p<512 holds row r=p>>2, global chunk (p&3)^((r>>1)&3).

// ---------------- proj_in: xp = x@W_in + b_in -> split bf16 (xph,xpl) --------------
// A = x f32 (reg-staged + on-the-fly split), B = Wth/Wtl [512][1024] (gload).
__global__ __launch_bounds__(256) void proj_in_mfma_kernel(
    const float* __restrict__ x, const ushort* __restrict__ Wth,
    const ushort* __restrict__ Wtl, const float* __restrict__ bias,
    ushort* __restrict__ xph, ushort* __restrict__ xpl) {
  __shared__ __align__(16) char smem[32768];
  const int t = threadIdx.x;
  const int wave = t >> 6, lane = t & 63;
  const int wm = wave >> 1, wn = wave & 1;
  const int lx = lane & 15, lg = lane >> 4;
  const int colBase = (int)blockIdx.x * 128;
  const size_t row0 = (size_t)blockIdx.y * 128;

  int rS[2], cS[2];
#pragma unroll
  for (int s = 0; s < 2; ++s) {
    int p = t + s * 256; rS[s] = p >> 2; cS[s] = (p & 3) ^ ((rS[s] >> 1) & 3);
  }
  size_t bbase[2];
#pragma unroll
  for (int s = 0; s < 2; ++s) bbase[s] = (size_t)(colBase + rS[s]) * DIMq + cS[s] * 8;

  int offm[4], offn[4];
#pragma unroll
  for (int f = 0; f < 4; ++f) {
    int sw = (lg ^ ((lx >> 1) & 3)) * 16;
    offm[f] = (wm * 64 + f * 16 + lx) * 64 + sw;
    offn[f] = (wn * 64 + f * 16 + lx) * 64 + sw;
  }

  f32x4 acc[4][4];
#pragma unroll
  for (int i = 0; i < 4; ++i)
#pragma unroll
    for (int j = 0; j < 4; ++j) acc[i][j] = (f32x4){0.f, 0.f, 0.f, 0.f};

#pragma unroll 1
  for (int kt = 0; kt < DIMq / 32; ++kt) {
    float4 f0[2], f1[2];
#pragma unroll
    for (int s = 0; s < 2; ++s) {
      const float* src = x + (row0 + rS[s]) * DIMq + kt * 32 + cS[s] * 8;
      f0[s] = *(const float4*)src; f1[s] = *(const float4*)(src + 4);
    }
    __syncthreads();
#pragma unroll
    for (int s = 0; s < 2; ++s) {
      int p16 = (t + s * 256) * 16;
      GL16(Wth + bbase[s] + kt * 32, smem + 16384 + p16);
      GL16(Wtl + bbase[s] + kt * 32, smem + 24576 + p16);
      float ff[8] = {f0[s].x, f0[s].y, f0[s].z, f0[s].w, f1[s].x, f1[s].y, f1[s].z, f1[s].w};
      union { bf16x8 v; ushort u[8]; } H, L;
#pragma unroll
      for (int j = 0; j < 8; ++j) {
        ushort h = bf16rne(ff[j]); H.u[j] = h; L.u[j] = bf16rne(ff[j] - bf16tof(h));
      }
      *(bf16x8*)(smem + p16) = H.v;
      *(bf16x8*)(smem + 8192 + p16) = L.v;
    }
    __syncthreads();
    bf16x8 ah[4], al_[4], bh[4], bl_[4];
#pragma unroll
    for (int f = 0; f < 4; ++f) {
      ah[f]  = *(const bf16x8*)(smem + offm[f]);
      al_[f] = *(const bf16x8*)(smem + 8192 + offm[f]);
      bh[f]  = *(const bf16x8*)(smem + 16384 + offn[f]);
      bl_[f] = *(const bf16x8*)(smem + 24576 + offn[f]);
    }
#pragma unroll
    for (int i = 0; i < 4; ++i)
#pragma unroll
      for (int j = 0; j < 4; ++j) {
        acc[i][j] = __builtin_amdgcn_mfma_f32_16x16x32_bf16(ah[i],  bh[j],  acc[i][j], 0, 0, 0);
        acc[i][j] = __builtin_amdgcn_mfma_f32_16x16x32_bf16(ah[i],  bl_[j], acc[i][j], 0, 0, 0);
        acc[i][j] = __builtin_amdgcn_mfma_f32_16x16x32_bf16(al_[i], bh[j],  acc[i][j], 0, 0, 0);
      }
  }
  // epilogue: +bias, split-store
#pragma unroll
  for (int nf = 0; nf < 4; ++nf) {
    int col = colBase + wn * 64 + nf * 16 + lx;
    float bv = bias[col];
#pragma unroll
    for (int mf = 0; mf < 4; ++mf)
#pragma unroll
      for (int q = 0; q < 4; ++q) {
        size_t row = row0 + wm * 64 + mf * 16 + lg * 4 + q;
        float v = acc[mf][nf][q] + bv;
        ushort h = bf16rne(v);
        xph[row * CDq + col] = h;
        xpl[row * CDq + col] = bf16rne(v - bf16tof(h));
      }
  }
}

// ---------------- EW = embed @ W_out + b_out  [8192][1024] f32 ---------------------
__global__ __launch_bounds__(256) void ew_mfma_kernel(
    const ushort* __restrict__ eh, const ushort* __restrict__ el,
    const ushort* __restrict__ Woth, const ushort* __restrict__ Wotl,
    const float* __restrict__ bias, float* __restrict__ EW) {
  __shared__ __align__(16) char smem[32768];
  const int t = threadIdx.x;
  const int wave = t >> 6, lane = t & 63;
  const int wm = wave >> 1, wn = wave & 1;
  const int lx = lane & 15, lg = lane >> 4;
  const int colBase = (int)blockIdx.x * 128;
  const size_t row0 = (size_t)blockIdx.y * 128;

  int rS[2], cS[2];
#pragma unroll
  for (int s = 0; s < 2; ++s) {
    int p = t + s * 256; rS[s] = p >> 2; cS[s] = (p & 3) ^ ((rS[s] >> 1) & 3);
  }
  size_t abase[2], bbase[2];
#pragma unroll
  for (int s = 0; s < 2; ++s) {
    abase[s] = (row0 + rS[s]) * CDq + cS[s] * 8;
    bbase[s] = (size_t)(colBase + rS[s]) * CDq + cS[s] * 8;
  }
  int offm[4], offn[4];
#pragma unroll
  for (int f = 0; f < 4; ++f) {
    int sw = (lg ^ ((lx >> 1) & 3)) * 16;
    offm[f] = (wm * 64 + f * 16 + lx) * 64 + sw;
    offn[f] = (wn * 64 + f * 16 + lx) * 64 + sw;
  }
  f32x4 acc[4][4];
#pragma unroll
  for (int i = 0; i < 4; ++i)
#pragma unroll
    for (int j = 0; j < 4; ++j) acc[i][j] = (f32x4){0.f, 0.f, 0.f, 0.f};

#pragma unroll 1
  for (int kt = 0; kt < CDq / 32; ++kt) {
    __syncthreads();
#pragma unroll
    for (int s = 0; s < 2; ++s) {
      int p16 = (t + s * 256) * 16;
      GL16(eh   + abase[s] + kt * 32, smem + p16);
      GL16(el   + abase[s] + kt * 32, smem + 8192 + p16);
      GL16(Woth + bbase[s] + kt * 32, smem + 16384 + p16);
      GL16(Wotl + bbase[s] + kt * 32, smem + 24576 + p16);
    }
    __syncthreads();
    bf16x8 ah[4], al_[4], bh[4], bl_[4];
#pragma unroll
    for (int f = 0; f < 4; ++f) {
      ah[f]  = *(const bf16x8*)(smem + offm[f]);
      al_[f] = *(const bf16x8*)(smem + 8192 + offm[f]);
      bh[f]  = *(const bf16x8*)(smem + 16384 + offn[f]);
      bl_[f] = *(const bf16x8*)(smem + 24576 + offn[f]);
    }
#pragma unroll
    for (int i = 0; i < 4; ++i)
#pragma unroll
      for (int j = 0; j < 4; ++j) {
        acc[i][j] = __builtin_amdgcn_mfma_f32_16x16x32_bf16(ah[i],  bh[j],  acc[i][j], 0, 0, 0);
        acc[i][j] = __builtin_amdgcn_mfma_f32_16x16x32_bf16(ah[i],  bl_[j], acc[i][j], 0, 0, 0);
        acc[i][j] = __builtin_amdgcn_mfma_f32_16x16x32_bf16(al_[i], bh[j],  acc[i][j], 0, 0, 0);
      }
  }
#pragma unroll
  for (int nf = 0; nf < 4; ++nf) {
    int col = colBase + wn * 64 + nf * 16 + lx;
    float bv = bias[col];
#pragma unroll
    for (int mf = 0; mf < 4; ++mf)
#pragma unroll
      for (int q = 0; q < 4; ++q) {
        size_t row = row0 + wm * 64 + mf * 16 + lg * 4 + q;
        EW[row * DIMq + col] = acc[mf][nf][q] + bv;
      }
  }
}

// ---------------- gather: out[row] = EW[ind[row]] ----------------
__global__ __launch_bounds__(256) void gather_out_kernel(const float* __restrict__ EW,
                                                         const int* __restrict__ ind,
                                                         float* __restrict__ out) {
  int row = blockIdx.x;
  const float4* src = (const float4*)(EW + (size_t)ind[row] * DIMq);
  float4* dst = (float4*)(out + (size_t)row * DIMq);
  dst[threadIdx.x] = src[threadIdx.x];
}

// ---------------- dist via split-bf16 MFMA, m97-style single buffer ----------------
// grid 1024 = 256 row-blocks x 4 codebook parts (2048 codes each), 16 tiles/part.
__global__ __launch_bounds__(256) void dist_mfma_kernel(
    const ushort* __restrict__ xph, const ushort* __restrict__ xpl,
    const ushort* __restrict__ eh,  const ushort* __restrict__ el,
    const float* __restrict__ sem,
    float* __restrict__ pb1, float* __restrict__ pb2, int* __restrict__ pidx) {
  __shared__ __align__(16) char smem[32768];
  const int t = threadIdx.x;
  const int wave = t >> 6, lane = t & 63;
  const int wm = wave >> 1, wn = wave & 1;
  const int lx = lane & 15, lg = lane >> 4;
  const int rb = (int)blockIdx.x >> 2, part = (int)blockIdx.x & 3;
  const size_t arow0 = (size_t)rb * 128;
  const int code0 = part * 2048;

  int rS[2], cS[2];
#pragma unroll
  for (int s = 0; s < 2; ++s) {
    int p = t + s * 256; rS[s] = p >> 2; cS[s] = (p & 3) ^ ((rS[s] >> 1) & 3);
  }
  size_t abase[2], bbase[2];
#pragma unroll
  for (int s = 0; s < 2; ++s) {
    abase[s] = (arow0 + rS[s]) * CDq + cS[s] * 8;
    bbase[s] = ((size_t)code0 + rS[s]) * CDq + cS[s] * 8;
  }
  int offm[4], offn[4];
#pragma unroll
  for (int f = 0; f < 4; ++f) {
    int sw = (lg ^ ((lx >> 1) & 3)) * 16;
    offm[f] = (wm * 64 + f * 16 + lx) * 64 + sw;
    offn[f] = (wn * 64 + f * 16 + lx) * 64 + sw;
  }

  float b1[16], b2[16]; int ic[16];
#pragma unroll
  for (int s = 0; s < 16; ++s) { b1[s] = -INFINITY; b2[s] = -INFINITY; ic[s] = 0; }

#pragma unroll 1
  for (int tile = 0; tile < 16; ++tile) {
    f32x4 acc[4][4];
#pragma unroll
    for (int i = 0; i < 4; ++i)
#pragma unroll
      for (int j = 0; j < 4; ++j) acc[i][j] = (f32x4){0.f, 0.f, 0.f, 0.f};
    const size_t tb = (size_t)tile * (128 * CDq);
#pragma unroll 1
    for (int kt = 0; kt < 16; ++kt) {
      __syncthreads();
#pragma unroll
      for (int s = 0; s < 2; ++s) {
        int p16 = (t + s * 256) * 16;
        GL16(xph + abase[s] + kt * 32,      smem + p16);
        GL16(xpl + abase[s] + kt * 32,      smem + 8192 + p16);
        GL16(eh  + bbase[s] + tb + kt * 32, smem + 16384 + p16);
        GL16(el  + bbase[s] + tb + kt * 32, smem + 24576 + p16);
      }
      __syncthreads();
      bf16x8 ah[4], al_[4], bh[4], bl_[4];
#pragma unroll
      for (int f = 0; f < 4; ++f) {
        ah[f]  = *(const bf16x8*)(smem + offm[f]);
        al_[f] = *(const bf16x8*)(smem + 8192 + offm[f]);
        bh[f]  = *(const bf16x8*)(smem + 16384 + offn[f]);
        bl_[f] = *(const bf16x8*)(smem + 24576 + offn[f]);
      }
#pragma unroll
      for (int i = 0; i < 4; ++i)
#pragma unroll
        for (int j = 0; j < 4; ++j) {
          acc[i][j] = __builtin_amdgcn_mfma_f32_16x16x32_bf16(ah[i],  bh[j],  acc[i][j], 0, 0, 0);
          acc[i][j] = __builtin_amdgcn_mfma_f32_16x16x32_bf16(ah[i],  bl_[j], acc[i][j], 0, 0, 0);
          acc[i][j] = __builtin_amdgcn_mfma_f32_16x16x32_bf16(al_[i], bh[j],  acc[i][j], 0, 0, 0);
        }
    }
    // epilogue: subtract seminorm, update running top-2 (codes ascend with nf)
#pragma unroll
    for (int nf = 0; nf < 4; ++nf) {
      int code = code0 + tile * 128 + wn * 64 + nf * 16 + lx;
      float sv = sem[code];
#pragma unroll
      for (int mf = 0; mf < 4; ++mf)
#pragma unroll
        for (int q = 0; q < 4; ++q) {
          float s = acc[mf][nf][q] - sv;
          int sl = mf * 4 + q;
          if (s > b1[sl]) { b2[sl] = b1[sl]; b1[sl] = s; ic[sl] = code; }
          else if (s > b2[sl]) b2[sl] = s;
        }
    }
  }

  // cross-lane (lx) top-2 reduce per slot within 16-lane groups
#pragma unroll
  for (int s = 0; s < 16; ++s) {
#pragma unroll
    for (int m = 1; m < 16; m <<= 1) {
      float o1 = __shfl_xor(b1[s], m, 16);
      float o2 = __shfl_xor(b2[s], m, 16);
      int   oi = __shfl_xor(ic[s], m, 16);
      bool ow = (o1 > b1[s]) || (o1 == b1[s] && oi < ic[s]);
      float l1 = ow ? b1[s] : o1;
      float w2 = ow ? o2 : b2[s];
      if (ow) { b1[s] = o1; ic[s] = oi; }
      b2[s] = fmaxf(w2, l1);
    }
  }
  __syncthreads();
  float* rb1 = (float*)smem;            // [2 wm][64 r][2 wn]
  float* rb2 = (float*)(smem + 1024);
  int*   ric = (int*)(smem + 2048);
  if (lx == 0) {
#pragma unroll
    for (int mf = 0; mf < 4; ++mf)
#pragma unroll
      for (int q = 0; q < 4; ++q) {
        int r64 = mf * 16 + lg * 4 + q;
        int o = wm * 128 + r64 * 2 + wn;
        int sl = mf * 4 + q;
        rb1[o] = b1[sl]; rb2[o] = b2[sl]; ric[o] = ic[sl];
      }
  }
  __syncthreads();
  if (t < 128) {
    int o0 = t * 2;
    float a1 = rb1[o0], a2 = rb2[o0]; int ai = ric[o0];
    float c1 = rb1[o0 + 1], c2 = rb2[o0 + 1]; int ci = ric[o0 + 1];
    float g1, g2; int gi;
    if (c1 > a1 || (c1 == a1 && ci < ai)) { g1 = c1; gi = ci; g2 = fmaxf(c2, a1); }
    else                                   { g1 = a1; gi = ai; g2 = fmaxf(a2, c1); }
    size_t o = (size_t)part * Mq + arow0 + t;
    pb1[o] = g1; pb2[o] = g2; pidx[o] = gi;
  }
}

// ---------------- merge 4 codebook parts -> ind, ind_f, near-tie flags -------------
__global__ __launch_bounds__(256) void merge_final_kernel(
    const float* __restrict__ pb1, const float* __restrict__ pb2, const int* __restrict__ pidx,
    int* __restrict__ ind, float* __restrict__ ind_f,
    int* __restrict__ flag_list, int* __restrict__ flag_cnt) {
  int row = blockIdx.x * 256 + threadIdx.x;
  if (row >= Mq) return;
  float g1 = pb1[row], g2 = pb2[row]; int gi = pidx[row];
#pragma unroll
  for (int part = 1; part < 4; ++part) {
    float c1 = pb1[(size_t)part * Mq + row], c2 = pb2[(size_t)part * Mq + row];
    int ci = pidx[(size_t)part * Mq + row];
    if (c1 > g1) { float og1 = g1; g1 = c1; gi = ci; g2 = fmaxf(og1, c2); }
    else         { g2 = fmaxf(g2, c1); }
  }
  ind[row] = gi;
  ind_f[row] = (float)gi;
  if (g1 - g2 < TAU) {
    int pos = atomicAdd(flag_cnt, 1);
    if (pos < FLAGCAP) flag_list[pos] = row;
  }
}

// ---------------- fp64 rescue of near-tie rows ----------------
__global__ __launch_bounds__(256) void rescue_kernel(
    const float* __restrict__ x, const float* __restrict__ W_in,
    const float* __restrict__ b_in, const float* __restrict__ embed,
    int* __restrict__ ind, float* __restrict__ ind_f,
    const int* __restrict__ flag_list, const int* __restrict__ flag_cnt) {
  __shared__ double xps[CDq];
  __shared__ double rb[256];
  __shared__ int ri[256];
  int cnt = *flag_cnt; if (cnt > FLAGCAP) cnt = FLAGCAP;
  for (int f = blockIdx.x; f < cnt; f += gridDim.x) {
    int row = flag_list[f];
    const float* xr = x + (size_t)row * DIMq;
    for (int c = threadIdx.x; c < CDq; c += 256) {
      double s0 = 0, s1 = 0;
      const float* wc = W_in + c;
      for (int d = 0; d < DIMq; d += 2) {
        s0 += (double)xr[d]     * (double)wc[(size_t)d * CDq];
        s1 += (double)xr[d + 1] * (double)wc[(size_t)(d + 1) * CDq];
      }
      xps[c] = s0 + s1 + (double)b_in[c];
    }
    __syncthreads();
    double best = -1e300; int bi = 0;
    for (int c0 = threadIdx.x; c0 < Kq; c0 += 256) {
      const float* e = embed + (size_t)c0 * CDq;
      double s0 = 0, s1 = 0, s2 = 0, s3 = 0;
      for (int d = 0; d < CDq; d += 4) {
        double e0 = e[d], e1 = e[d + 1], e2 = e[d + 2], e3 = e[d + 3];
        s0 += e0 * (xps[d]     - 0.5 * e0);
        s1 += e1 * (xps[d + 1] - 0.5 * e1);
        s2 += e2 * (xps[d + 2] - 0.5 * e2);
        s3 += e3 * (xps[d + 3] - 0.5 * e3);
      }
      double s = (s0 + s1) + (s2 + s3);
      if (s > best) { best = s; bi = c0; }
    }
    rb[threadIdx.x] = best; ri[threadIdx.x] = bi;
    __syncthreads();
    if (threadIdx.x == 0) {
      double g = -1e300; int gi = 0;
      for (int q = 0; q < 256; ++q)
        if (rb[q] > g || (rb[q] == g && ri[q] < gi)) { g = rb[q]; gi = ri[q]; }
      ind[row] = gi;
      ind_f[row] = (float)gi;
    }
    __syncthreads();
  }
}

// ---------------- commit loss (vectorized) ----------------
__global__ __launch_bounds__(256) void loss_kernel(const ushort* __restrict__ xph,
                                                   const ushort* __restrict__ xpl,
                                                   const float* __restrict__ embed,
                                                   const int* __restrict__ ind,
                                                   float* __restrict__ partials) {
  int wave = threadIdx.x >> 6, lane = threadIdx.x & 63;
  float s = 0.f;
#pragma unroll 1
  for (int i = 0; i < 8; ++i) {
    int row = blockIdx.x * 32 + wave * 8 + i;
    size_t o = (size_t)row * CDq + lane * 8;
    u16x4 h0 = *(const u16x4*)(xph + o), h1 = *(const u16x4*)(xph + o + 4);
    u16x4 l0 = *(const u16x4*)(xpl + o), l1 = *(const u16x4*)(xpl + o + 4);
    const float* er = embed + (size_t)ind[row] * CDq + lane * 8;
    float4 e0 = *(const float4*)er, e1 = *(const float4*)(er + 4);
    float ee[8] = {e0.x, e0.y, e0.z, e0.w, e1.x, e1.y, e1.z, e1.w};
#pragma unroll
    for (int j = 0; j < 4; ++j) {
      float d0 = ee[j]     - (bf16tof(h0[j]) + bf16tof(l0[j]));
      float d1 = ee[4 + j] - (bf16tof(h1[j]) + bf16tof(l1[j]));
      s = fmaf(d0, d0, s); s = fmaf(d1, d1, s);
    }
  }
#pragma unroll
  for (int off = 32; off; off >>= 1) s += __shfl_down(s, off, 64);
  __shared__ float red[4];
  if (lane == 0) red[wave] = s;
  __syncthreads();
  if (threadIdx.x == 0) partials[blockIdx.x] = red[0] + red[1] + red[2] + red[3];
}

__global__ __launch_bounds__(256) void loss_final_kernel(const float* __restrict__ partials,
                                                         float* __restrict__ out_loss) {
  __shared__ double red[256];
  double s = 0;
  for (int i = threadIdx.x; i < 1024; i += 256) s += (double)partials[i];
  red[threadIdx.x] = s; __syncthreads();
  for (int off = 128; off; off >>= 1) {
    if (threadIdx.x < off) red[threadIdx.x] += red[threadIdx.x + off];
    __syncthreads();
  }
  if (threadIdx.x == 0) *out_loss = (float)(red[0] / 16777216.0);
}

// ---------------- fallback f32 proj_out (if ws too small for EW) ----------------
__global__ __launch_bounds__(256) void proj_out_f32_kernel(
    const float* __restrict__ A, const float* __restrict__ Bw,
    const float* __restrict__ bias, float* __restrict__ C,
    const int* __restrict__ gidx) {
  __shared__ float As[16][68];
  __shared__ float Bs[16][132];
  const int t = threadIdx.x, tx = t & 15, ty = t >> 4;
  const int rowBase = blockIdx.y * 64;
  const int colBase = blockIdx.x * 128;
  const int rA = t >> 2, kqA = (t & 3) * 4;
  const int kB = t >> 4, cB = (t & 15) * 8;
  const float* Arow = A + (size_t)gidx[rowBase + rA] * CDq;
  const float* Bp = Bw + (size_t)kB * DIMq + colBase + cB;
  float acc[4][8] = {};
  for (int kt = 0; kt < CDq; kt += 16) {
    float4 av = *(const float4*)(Arow + kt + kqA);
    float4 b0 = *(const float4*)(Bp + (size_t)kt * DIMq);
    float4 b1 = *(const float4*)(Bp + (size_t)kt * DIMq + 4);
    __syncthreads();
    As[kqA + 0][rA] = av.x; As[kqA + 1][rA] = av.y;
    As[kqA + 2][rA] = av.z; As[kqA + 3][rA] = av.w;
    *(float4*)&Bs[kB][cB]     = b0;
    *(float4*)&Bs[kB][cB + 4] = b1;
    __syncthreads();
#pragma unroll
    for (int kk = 0; kk < 16; ++kk) {
      float4 a  = *(const float4*)&As[kk][ty * 4];
      float4 p0 = *(const float4*)&Bs[kk][tx * 4];
      float4 p1 = *(const float4*)&Bs[kk][64 + tx * 4];
      float ar[4] = {a.x, a.y, a.z, a.w};
      float br[8] = {p0.x, p0.y, p0.z, p0.w, p1.x, p1.y, p1.z, p1.w};
#pragma unroll
      for (int i = 0; i < 4; ++i)
#pragma unroll
        for (int j = 0; j < 8; ++j) acc[i][j] = fmaf(ar[i], br[j], acc[i][j]);
    }
  }
  float4 bi0 = *(const float4*)(bias + colBase + tx * 4);
  float4 bi1 = *(const float4*)(bias + colBase + 64 + tx * 4);
#pragma unroll
  for (int i = 0; i < 4; ++i) {
    int row = rowBase + ty * 4 + i;
    float4 o0 = {acc[i][0] + bi0.x, acc[i][1] + bi0.y, acc[i][2] + bi0.z, acc[i][3] + bi0.w};
    float4 o1 = {acc[i][4] + bi1.x, acc[i][5] + bi1.y, acc[i][6] + bi1.z, acc[i][7] + bi1.w};
    *(float4*)(C + (size_t)row * DIMq + colBase + tx * 4)      = o0;
    *(float4*)(C + (size_t)row * DIMq + colBase + 64 + tx * 4) = o1;
  }
}

extern "C" void kernel_launch(void* const* d_in, const int* in_sizes, int n_in,
                              void* d_out, int out_size, void* d_ws, size_t ws_size,
                              hipStream_t stream) {
  const float* x     = (const float*)d_in[0];
  const float* W_in  = (const float*)d_in[1];
  const float* b_in  = (const float*)d_in[2];
  const float* embed = (const float*)d_in[3];
  const float* W_out = (const float*)d_in[4];
  const float* b_out = (const float*)d_in[5];

  char* ob = (char*)d_out;
  float*  out   = (float*)d_out;
  ushort* xph   = (ushort*)ob;                            // [0,32MiB)
  ushort* xpl   = (ushort*)(ob + (size_t)32 * MiB);       // [32,64)
  ushort* eh    = (ushort*)(ob + (size_t)64 * MiB);       // [64,72)
  ushort* el    = (ushort*)(ob + (size_t)72 * MiB);       // [72,80)
  ushort* Wth   = (ushort*)(ob + (size_t)80 * MiB);       // [80,81)
  ushort* Wtl   = (ushort*)(ob + (size_t)81 * MiB);       // [81,82)
  ushort* Woth  = (ushort*)(ob + (size_t)82 * MiB);       // [82,83)
  ushort* Wotl  = (ushort*)(ob + (size_t)83 * MiB);       // [83,84)
  float*  pb1   = (float*)(ob + (size_t)84 * MiB);        // 4*Mq floats
  float*  pb2   = pb1 + 4 * (size_t)Mq;
  int*    pidx  = (int*)(pb2 + 4 * (size_t)Mq);
  float*  ind_f = out + (size_t)Mq * DIMq;
  float*  loss_out = ind_f + Mq;

  char* ws = (char*)d_ws;
  int*   flag_cnt  = (int*)ws;
  int*   ind       = (int*)(ws + 64);
  int*   flag_list = (int*)(ws + 64 + (size_t)Mq * 4);
  float* sem       = (float*)(ws + 64 + (size_t)Mq * 4 + FLAGCAP * 4);
  float* partials  = sem + Kq;
  float* EW        = (float*)(ws + (size_t)1 * MiB);      // 32 MiB, only if ws is big
  const bool big_ws = ws_size >= (size_t)36 * MiB;

  (void)hipMemsetAsync(flag_cnt, 0, 4, stream);
  embed_conv_kernel<<<(Kq * CDq) / (256 * 8), 256, 0, stream>>>(embed, eh, el);
  seminorm_kernel<<<Kq / 4, 256, 0, stream>>>(embed, sem);
  transpose_split_kernel<<<dim3(CDq / 64, DIMq / 64), 256, 0, stream>>>(W_in, Wth, Wtl, DIMq, CDq);
  transpose_split_kernel<<<dim3(DIMq / 64, CDq / 64), 256, 0, stream>>>(W_out, Woth, Wotl, CDq, DIMq);
  if (big_ws)
    ew_mfma_kernel<<<dim3(DIMq / 128, Kq / 128), 256, 0, stream>>>(eh, el, Woth, Wotl, b_out, EW);
  proj_in_mfma_kernel<<<dim3(CDq / 128, Mq / 128), 256, 0, stream>>>(x, Wth, Wtl, b_in, xph, xpl);
  dist_mfma_kernel<<<Mq / 128 * 4, 256, 0, stream>>>(xph, xpl, eh, el, sem, pb1, pb2, pidx);
  merge_final_kernel<<<Mq / 256, 256, 0, stream>>>(pb1, pb2, pidx, ind, ind_f, flag_list, flag_cnt);
  rescue_kernel<<<256, 256, 0, stream>>>(x, W_in, b_in, embed, ind, ind_f, flag_list, flag_cnt);
  loss_kernel<<<Mq / 32, 256, 0, stream>>>(xph, xpl, embed, ind, partials);
  loss_final_kernel<<<1, 256, 0, stream>>>(partials, loss_out);
  if (big_ws)
    gather_out_kernel<<<Mq, 256, 0, stream>>>(EW, ind, out);
  else
    proj_out_f32_kernel<<<dim3(DIMq / 128, Mq / 64), 256, 0, stream>>>(embed, W_out, b_out, out, ind);
}